// Round 1
// baseline (69.326 us; speedup 1.0000x reference)
//
#include <hip/hip_runtime.h>
#include <stdint.h>

// out[b,i] = x[b,i] * (sum_j x[b,j] * W[i,j]) + bias[i]
// GEMM: C = X (1024x512) · W^T (512x512), NT layout (both K-contiguous).
// bf16 MFMA (threshold 5.12 allows bf16 rounding), fp32 epilogue multiply.

#define LATENT 512
#define BATCH  1024
#define BM 64          // block tile M (batch)
#define BN 32          // block tile N (output dim)
#define BK 64          // K chunk per LDS stage
#define LDK (BK + 8)   // +8 bf16 pad: keeps 16B row alignment, 2-way-max bank conflicts

typedef short bf16x8 __attribute__((ext_vector_type(8)));   // 8 bf16 in 4 VGPRs
typedef float f32x4  __attribute__((ext_vector_type(4)));

__device__ __forceinline__ short f2bf(float f) {
    // round-to-nearest-even fp32 -> bf16 (inputs are finite normals)
    uint32_t u = __builtin_bit_cast(uint32_t, f);
    u += 0x7FFFu + ((u >> 16) & 1u);
    return (short)(u >> 16);
}

__global__ __launch_bounds__(128) void filnp_kernel(
    const float* __restrict__ X, const float* __restrict__ W,
    const float* __restrict__ bias, float* __restrict__ out)
{
    __shared__ short As[BM][LDK];   // X tile, bf16
    __shared__ short Bs[BN][LDK];   // W tile, bf16

    const int tid  = threadIdx.x;
    const int lane = tid & 63;
    const int wv   = tid >> 6;          // wave 0..1 -> M halves of block tile
    const int n0   = blockIdx.x * BN;
    const int m0   = blockIdx.y * BM;

    const int qrow = lane >> 4;         // 0..3
    const int lrow = lane & 15;

    f32x4 acc[2][2] = {};               // [mi][ni] 16x16 frags -> wave tile 32x32

    // staging maps (128 threads):
    //   A: 64 rows x 64 cols, thread t: row t>>1, 32 floats at (t&1)*32
    //   B: 32 rows x 64 cols, thread t: row t>>2, 16 floats at (t&3)*16
    const int ar = tid >> 1;
    const int ac = (tid & 1) * 32;
    const int br = tid >> 2;
    const int bc = (tid & 3) * 16;

    for (int kt = 0; kt < LATENT / BK; ++kt) {
        const int k0 = kt * BK;

        // ---- stage A (X) ----
        {
            const float* src = X + (size_t)(m0 + ar) * LATENT + k0 + ac;
            float av[32];
            #pragma unroll
            for (int i = 0; i < 8; ++i)
                ((f32x4*)av)[i] = ((const f32x4*)src)[i];
            short bv[32];
            #pragma unroll
            for (int i = 0; i < 32; ++i) bv[i] = f2bf(av[i]);
            #pragma unroll
            for (int i = 0; i < 4; ++i)
                *(bf16x8*)&As[ar][ac + i * 8] = ((bf16x8*)bv)[i];
        }
        // ---- stage B (W) ----
        {
            const float* src = W + (size_t)(n0 + br) * LATENT + k0 + bc;
            float av[16];
            #pragma unroll
            for (int i = 0; i < 4; ++i)
                ((f32x4*)av)[i] = ((const f32x4*)src)[i];
            short bv[16];
            #pragma unroll
            for (int i = 0; i < 16; ++i) bv[i] = f2bf(av[i]);
            #pragma unroll
            for (int i = 0; i < 2; ++i)
                *(bf16x8*)&Bs[br][bc + i * 8] = ((bf16x8*)bv)[i];
        }
        __syncthreads();

        // ---- MFMA over this K chunk ----
        #pragma unroll
        for (int ks = 0; ks < BK / 32; ++ks) {
            const int kc = ks * 32 + qrow * 8;
            bf16x8 a0 = *(const bf16x8*)&As[wv * 32 +      lrow][kc];
            bf16x8 a1 = *(const bf16x8*)&As[wv * 32 + 16 + lrow][kc];
            bf16x8 b0 = *(const bf16x8*)&Bs[     lrow][kc];
            bf16x8 b1 = *(const bf16x8*)&Bs[16 + lrow][kc];
            acc[0][0] = __builtin_amdgcn_mfma_f32_16x16x32_bf16(a0, b0, acc[0][0], 0, 0, 0);
            acc[0][1] = __builtin_amdgcn_mfma_f32_16x16x32_bf16(a0, b1, acc[0][1], 0, 0, 0);
            acc[1][0] = __builtin_amdgcn_mfma_f32_16x16x32_bf16(a1, b0, acc[1][0], 0, 0, 0);
            acc[1][1] = __builtin_amdgcn_mfma_f32_16x16x32_bf16(a1, b1, acc[1][1], 0, 0, 0);
        }
        __syncthreads();
    }

    // ---- epilogue: out = x * wx + bias (fp32 multiply for accuracy) ----
    #pragma unroll
    for (int mi = 0; mi < 2; ++mi) {
        #pragma unroll
        for (int ni = 0; ni < 2; ++ni) {
            #pragma unroll
            for (int r = 0; r < 4; ++r) {
                const int m = m0 + wv * 32 + mi * 16 + qrow * 4 + r;
                const int n = n0 + ni * 16 + lrow;
                const float wx = acc[mi][ni][r];
                out[(size_t)m * LATENT + n] = X[(size_t)m * LATENT + n] * wx + bias[n];
            }
        }
    }
}

extern "C" void kernel_launch(void* const* d_in, const int* in_sizes, int n_in,
                              void* d_out, int out_size, void* d_ws, size_t ws_size,
                              hipStream_t stream) {
    const float* X    = (const float*)d_in[0];   // (1024, 512)
    const float* W    = (const float*)d_in[1];   // (512, 512)
    const float* bias = (const float*)d_in[2];   // (512,)
    float* out        = (float*)d_out;           // (1024, 512)

    dim3 grid(LATENT / BN, BATCH / BM);          // (16, 16) = 256 blocks
    filnp_kernel<<<grid, 128, 0, stream>>>(X, W, bias, out);
}

// Round 2
// 67.487 us; speedup vs baseline: 1.0273x; 1.0273x over previous
//
#include <hip/hip_runtime.h>
#include <stdint.h>

// out[b,i] = x[b,i] * (sum_j x[b,j] * W[i,j]) + bias[i]
// Two-phase: (1) convert X,W fp32->bf16 into ws; (2) LDS-free MFMA GEMM,
// one wave per 16x16 output tile, direct global->register fragment loads,
// fused fp32 epilogue. No barriers anywhere; 2048 waves for latency hiding.

#define LATENT 512
#define BATCH  1024
#define XN (BATCH * LATENT)    // 524288 floats
#define WN (LATENT * LATENT)   // 262144 floats

typedef short bf16x8 __attribute__((ext_vector_type(8)));   // 8 bf16, 4 VGPRs
typedef float f32x4  __attribute__((ext_vector_type(4)));

__device__ __forceinline__ short f2bf(float f) {
    // RNE fp32 -> bf16 (finite normals)
    uint32_t u = __builtin_bit_cast(uint32_t, f);
    u += 0x7FFFu + ((u >> 16) & 1u);
    return (short)(u >> 16);
}

// ---- Kernel 1: convert X (524288 f) and W (262144 f) to bf16 in ws ----
// 8 floats/thread, 786432/8 = 98304 threads = 384 blocks x 256.
// XN divisible by 2048 (block*8) -> no intra-block src divergence.
__global__ __launch_bounds__(256) void convert_kernel(
    const float* __restrict__ X, const float* __restrict__ W,
    short* __restrict__ Xb, short* __restrict__ Wb)
{
    const int g = (blockIdx.x * 256 + threadIdx.x) * 8;
    const float* src;
    short* dst;
    if (g < XN) { src = X + g;        dst = Xb + g; }
    else        { src = W + (g - XN); dst = Wb + (g - XN); }
    f32x4 v0 = ((const f32x4*)src)[0];
    f32x4 v1 = ((const f32x4*)src)[1];
    short s[8];
    #pragma unroll
    for (int i = 0; i < 4; ++i) s[i]     = f2bf(v0[i]);
    #pragma unroll
    for (int i = 0; i < 4; ++i) s[4 + i] = f2bf(v1[i]);
    *(bf16x8*)dst = *(bf16x8*)s;
}

// ---- Kernel 2: GEMM C = Xb · Wb^T with fused epilogue ----
// Wave tile 16x16, K=512 in 16 MFMA steps. Block = 4 waves in a 2x2
// arrangement (32x32 block tile) so fragment streams share L1.
__global__ __launch_bounds__(256) void gemm_kernel(
    const short* __restrict__ Xb, const short* __restrict__ Wb,
    const float* __restrict__ X, const float* __restrict__ bias,
    float* __restrict__ out)
{
    const int tid  = threadIdx.x;
    const int lane = tid & 63;
    const int wv   = tid >> 6;                      // 0..3
    const int m0   = blockIdx.y * 32 + (wv >> 1) * 16;
    const int n0   = blockIdx.x * 32 + (wv & 1) * 16;
    const int lrow = lane & 15;
    const int q    = lane >> 4;                     // 0..3

    // A[m=lane&15][k=q*8+j], B[n=lane&15][k=q*8+j]; rows K-contiguous.
    const short* ap = Xb + (size_t)(m0 + lrow) * LATENT + q * 8;
    const short* bp = Wb + (size_t)(n0 + lrow) * LATENT + q * 8;

    f32x4 acc = {};
    #pragma unroll
    for (int ks = 0; ks < 16; ++ks) {
        bf16x8 a = *(const bf16x8*)(ap + ks * 32);  // 64B imm offsets
        bf16x8 b = *(const bf16x8*)(bp + ks * 32);
        acc = __builtin_amdgcn_mfma_f32_16x16x32_bf16(a, b, acc, 0, 0, 0);
    }

    // C/D: col = lane&15, row = q*4 + reg. Epilogue in fp32.
    #pragma unroll
    for (int r = 0; r < 4; ++r) {
        const int m = m0 + q * 4 + r;
        const int n = n0 + lrow;
        out[(size_t)m * LATENT + n] = X[(size_t)m * LATENT + n] * acc[r] + bias[n];
    }
}

extern "C" void kernel_launch(void* const* d_in, const int* in_sizes, int n_in,
                              void* d_out, int out_size, void* d_ws, size_t ws_size,
                              hipStream_t stream) {
    const float* X    = (const float*)d_in[0];   // (1024, 512)
    const float* W    = (const float*)d_in[1];   // (512, 512)
    const float* bias = (const float*)d_in[2];   // (512,)
    float* out        = (float*)d_out;           // (1024, 512)

    short* Xb = (short*)d_ws;                    // 1 MiB
    short* Wb = (short*)d_ws + XN;               // 512 KiB

    convert_kernel<<<(XN + WN) / 8 / 256, 256, 0, stream>>>(X, W, Xb, Wb);
    gemm_kernel<<<dim3(LATENT / 32, BATCH / 32), 256, 0, stream>>>(Xb, Wb, X, bias, out);
}